// Round 3
// baseline (345.391 us; speedup 1.0000x reference)
//
#include <hip/hip_runtime.h>

typedef unsigned short ushort_t;
typedef __attribute__((ext_vector_type(8))) short short8;
typedef __attribute__((ext_vector_type(4))) short s16x4;
typedef __attribute__((ext_vector_type(4))) float f32x4;

#define N_NODES 50000
#define NBASE   4
#define N_EDGE  320000
#define DM_BLOCKS 2048
#define N_GROUPS (N_EDGE / 8)
#define SCAN_BLOCKS 49          // 49*1024 = 50176 >= 50000
#define TILE_M  32
#define YSTRIDE 520             // 512 + 8 ushorts pad (stride 1040B = 260 dwords == 4 mod 32)

// canonical fp32 small-tensor layout (element offsets)
#define C_COMP1 0
#define C_COMP2 100
#define C_BIAS1 200
#define C_BIAS2 328
#define C_REL   456
#define C_EBIAS 1992
#define C_TOTAL 2120

__device__ __forceinline__ float bf2f(ushort_t u) {
    union { unsigned int i; float f; } v; v.i = ((unsigned int)u) << 16; return v.f;
}
__device__ __forceinline__ ushort_t f2bf(float f) {
    union { float f; unsigned int i; } v; v.f = f;
    unsigned int u = v.i;
    u = (u + 0x7FFFu + ((u >> 16) & 1u)) >> 16;   // RNE
    return (ushort_t)u;
}
__device__ __forceinline__ float readf(const void* p, int i, int isbf) {
    return isbf ? bf2f(((const ushort_t*)p)[i]) : ((const float*)p)[i];
}
__device__ __forceinline__ float softplus(float x) {
    if (x > 20.f) return x;
    if (x < -20.f) return expf(x);
    return log1pf(expf(x));
}

// Fused: detect float dtype of emb (phase 1) + canonicalize small tensors (phase 2).
__global__ void k_prep(const ushort_t* __restrict__ emb, int* __restrict__ flag,
                       const void* comp1, const void* comp2, const void* b1, const void* b2,
                       const void* rel, const void* eb, float* __restrict__ canon) {
    __shared__ int cnt;
    if (threadIdx.x == 0) cnt = 0;
    __syncthreads();
    int e = (emb[threadIdx.x] >> 7) & 0xFF;
    if (e >= 100 && e <= 126) atomicAdd(&cnt, 1);
    __syncthreads();
    if (threadIdx.x == 0) *flag = (cnt >= 200) ? 1 : 0;  // 1 = bf16 inputs
    __syncthreads();
    int isbf = (cnt >= 200) ? 1 : 0;
    for (int i = threadIdx.x; i < C_TOTAL; i += blockDim.x) {
        float v;
        if      (i < C_COMP2) v = readf(comp1, i - C_COMP1, isbf);
        else if (i < C_BIAS1) v = readf(comp2, i - C_COMP2, isbf);
        else if (i < C_BIAS2) v = readf(b1,    i - C_BIAS1, isbf);
        else if (i < C_REL)   v = readf(b2,    i - C_BIAS2, isbf);
        else if (i < C_EBIAS) v = readf(rel,   i - C_REL,   isbf);
        else                  v = readf(eb,    i - C_EBIAS, isbf);
        canon[i] = v;
    }
}

// Fused init: blocks [0,256)   -> repack bases1 -> btK1[o][b*128+i]
//             blocks [256,512) -> repack bases2 -> btK2
//             blocks [512, ..) -> x = bf16(relu(emb + ebias))
__global__ void k_init(const void* __restrict__ bases1, ushort_t* __restrict__ btK1,
                       const void* __restrict__ bases2, ushort_t* __restrict__ btK2,
                       const void* __restrict__ emb, const float* __restrict__ canon,
                       ushort_t* __restrict__ x, const int* __restrict__ flag) {
    int isbf = *flag;
    int bid = blockIdx.x;
    if (bid < 512) {
        const void* bases = (bid < 256) ? bases1 : bases2;
        ushort_t* btK = (bid < 256) ? btK1 : btK2;
        int idx = (bid & 255) * 256 + threadIdx.x;      // < 65536
        int b = idx >> 14, i = (idx >> 7) & 127, o = idx & 127;
        btK[(size_t)o * 512 + (b << 7) + i] = f2bf(readf(bases, idx, isbf));
    } else {
        int i = (bid - 512) * 256 + threadIdx.x;
        if (i < N_NODES * 128) {
            float v = readf(emb, i, isbf) + canon[C_EBIAS + (i & 127)];
            x[i] = f2bf(fmaxf(v, 0.f));
        }
    }
}

// ---------------- CSR build (dst-indexed) ----------------
__global__ void k_cnt(const int* __restrict__ ei, int* __restrict__ cnt) {
    int e = blockIdx.x * blockDim.x + threadIdx.x;
    if (e >= N_EDGE) return;
    atomicAdd(&cnt[ei[N_EDGE + e]], 1);
}

__global__ void k_scan1(const int* __restrict__ cnt, int* __restrict__ ptr,
                        int* __restrict__ bsum) {
    __shared__ int s[1024];
    int t = threadIdx.x;
    int i = blockIdx.x * 1024 + t;
    int v = (i < N_NODES) ? cnt[i] : 0;
    s[t] = v;
    __syncthreads();
    for (int off = 1; off < 1024; off <<= 1) {
        int u = (t >= off) ? s[t - off] : 0;
        __syncthreads();
        s[t] += u;
        __syncthreads();
    }
    if (i < N_NODES) ptr[i] = s[t] - v;
    if (t == 1023) bsum[blockIdx.x] = s[1023];
}

__global__ void k_scan2(const int* __restrict__ bsum, int* __restrict__ boff) {
    int t = threadIdx.x;                        // 64
    int v = (t < SCAN_BLOCKS) ? bsum[t] : 0;
    int orig = v;
    #pragma unroll
    for (int off = 1; off < 64; off <<= 1) {
        int u = __shfl_up(v, off);
        if (t >= off) v += u;
    }
    boff[t] = v - orig;
}

__global__ void k_scan3(int* __restrict__ ptr, int* __restrict__ cursor,
                        const int* __restrict__ boff) {
    int t = threadIdx.x;
    int i = blockIdx.x * 1024 + t;
    if (i < N_NODES) {
        int p = ptr[i] + boff[blockIdx.x];
        ptr[i] = p;
        cursor[i] = p;
    }
    if (blockIdx.x == 0 && t == 0) ptr[N_NODES] = N_EDGE;
}

__global__ void k_fill(const int* __restrict__ ei, const int* __restrict__ et,
                       int* __restrict__ cursor, unsigned int* __restrict__ packed) {
    int e = blockIdx.x * blockDim.x + threadIdx.x;
    if (e >= N_EDGE) return;
    int dst = ei[N_EDGE + e];
    int pos = atomicAdd(&cursor[dst], 1);
    packed[pos] = (unsigned int)(ei[e] & 0xFFFF) | ((unsigned int)et[e] << 16);
}

// ---------------- FUSED layer: agg (x-gather -> LDS y-tile) + GEMM + epilogue ----------------
// Phase A: y[ml, b*128+c] = sum_{e in CSR[m]} comp[r_e, b] * x[src_e, c]   (bf16, LDS)
//          one node per half-wave, lane owns cols c0..c0+3 (8B loads)
// Phase B: out[32 x 128] = y_tile[32 x 512] @ W   (A from LDS, B-frags from global btK, L2-hot)
// Epilogue: /deg + bias (+relu), scalar bf16 stores.
__global__ __launch_bounds__(256) void
k_fused(const ushort_t* __restrict__ x, const int* __restrict__ ptr,
        const unsigned int* __restrict__ packed, const float* __restrict__ compf,
        const ushort_t* __restrict__ btK, const int* __restrict__ cnt,
        const float* __restrict__ canon, ushort_t* __restrict__ xout,
        int cbias, int dorelu) {
    __shared__ __align__(16) ushort_t yt[TILE_M * YSTRIDE];   // 33,280 B
    __shared__ __align__(16) float sc[100];
    int tid = threadIdx.x;
    for (int i = tid; i < 100; i += 256) sc[i] = compf[i];
    __syncthreads();

    int m0 = blockIdx.x * TILE_M;
    int hw = tid >> 5;                      // half-wave id 0..7
    int li = tid & 31;
    int c0 = li << 2;                       // lane owns x-cols c0..c0+3

    // ---- Phase A: aggregate 4 nodes per half-wave into LDS y-tile ----
    for (int j = 0; j < 4; ++j) {
        int ml = hw * 4 + j;
        int m = m0 + ml;
        float acc[4][4];                    // [base][col]
        #pragma unroll
        for (int b = 0; b < 4; ++b)
            #pragma unroll
            for (int jj = 0; jj < 4; ++jj) acc[b][jj] = 0.f;

        if (m < N_NODES) {
            int beg = ptr[m], end = ptr[m + 1];
            int i = beg;
            for (; i + 4 <= end; i += 4) {
                unsigned int p0 = packed[i], p1 = packed[i + 1];
                unsigned int p2 = packed[i + 2], p3 = packed[i + 3];
                s16x4 w0 = *(const s16x4*)(x + (size_t)(p0 & 0xFFFFu) * 128 + c0);
                s16x4 w1 = *(const s16x4*)(x + (size_t)(p1 & 0xFFFFu) * 128 + c0);
                s16x4 w2 = *(const s16x4*)(x + (size_t)(p2 & 0xFFFFu) * 128 + c0);
                s16x4 w3 = *(const s16x4*)(x + (size_t)(p3 & 0xFFFFu) * 128 + c0);
                f32x4 cc0 = *(const f32x4*)(sc + (p0 >> 16) * 4);
                f32x4 cc1 = *(const f32x4*)(sc + (p1 >> 16) * 4);
                f32x4 cc2 = *(const f32x4*)(sc + (p2 >> 16) * 4);
                f32x4 cc3 = *(const f32x4*)(sc + (p3 >> 16) * 4);
                #pragma unroll
                for (int jj = 0; jj < 4; ++jj) {
                    float v = bf2f((ushort_t)((const short*)&w0)[jj]);
                    acc[0][jj] += cc0[0] * v; acc[1][jj] += cc0[1] * v;
                    acc[2][jj] += cc0[2] * v; acc[3][jj] += cc0[3] * v;
                }
                #pragma unroll
                for (int jj = 0; jj < 4; ++jj) {
                    float v = bf2f((ushort_t)((const short*)&w1)[jj]);
                    acc[0][jj] += cc1[0] * v; acc[1][jj] += cc1[1] * v;
                    acc[2][jj] += cc1[2] * v; acc[3][jj] += cc1[3] * v;
                }
                #pragma unroll
                for (int jj = 0; jj < 4; ++jj) {
                    float v = bf2f((ushort_t)((const short*)&w2)[jj]);
                    acc[0][jj] += cc2[0] * v; acc[1][jj] += cc2[1] * v;
                    acc[2][jj] += cc2[2] * v; acc[3][jj] += cc2[3] * v;
                }
                #pragma unroll
                for (int jj = 0; jj < 4; ++jj) {
                    float v = bf2f((ushort_t)((const short*)&w3)[jj]);
                    acc[0][jj] += cc3[0] * v; acc[1][jj] += cc3[1] * v;
                    acc[2][jj] += cc3[2] * v; acc[3][jj] += cc3[3] * v;
                }
            }
            for (; i < end; ++i) {
                unsigned int p0 = packed[i];
                s16x4 w0 = *(const s16x4*)(x + (size_t)(p0 & 0xFFFFu) * 128 + c0);
                f32x4 cc0 = *(const f32x4*)(sc + (p0 >> 16) * 4);
                #pragma unroll
                for (int jj = 0; jj < 4; ++jj) {
                    float v = bf2f((ushort_t)((const short*)&w0)[jj]);
                    acc[0][jj] += cc0[0] * v; acc[1][jj] += cc0[1] * v;
                    acc[2][jj] += cc0[2] * v; acc[3][jj] += cc0[3] * v;
                }
            }
        }
        ushort_t* yrow = yt + ml * YSTRIDE;
        #pragma unroll
        for (int b = 0; b < 4; ++b) {
            unsigned int lo = (unsigned int)f2bf(acc[b][0]) | ((unsigned int)f2bf(acc[b][1]) << 16);
            unsigned int hi = (unsigned int)f2bf(acc[b][2]) | ((unsigned int)f2bf(acc[b][3]) << 16);
            unsigned int* yp = (unsigned int*)(yrow + (b << 7) + c0);
            yp[0] = lo;
            yp[1] = hi;
        }
    }
    __syncthreads();

    // ---- Phase B: GEMM 32x512 @ 512x128 ----
    int lane = tid & 63, w = tid >> 6;
    int r = lane & 15, q = lane >> 4;
    int wr = w & 1, wc = w >> 1;            // wave -> (row-tile, col-half)
    f32x4 gacc[4] = {};
    const ushort_t* arow = yt + (wr * 16 + r) * YSTRIDE + q * 8;
    const ushort_t* bbase = btK + (size_t)(wc * 64 + r) * 512 + q * 8;
    #pragma unroll
    for (int step = 0; step < 16; ++step) {
        short8 a = *(const short8*)(arow + step * 32);
        #pragma unroll
        for (int t = 0; t < 4; ++t) {
            short8 b = *(const short8*)(bbase + t * 16 * 512 + step * 32);
            gacc[t] = __builtin_amdgcn_mfma_f32_16x16x32_bf16(a, b, gacc[t], 0, 0, 0);
        }
    }

    // ---- Epilogue ----
    int rbase = m0 + wr * 16 + (q << 2);
    float d[4];
    #pragma unroll
    for (int ii = 0; ii < 4; ++ii) {
        int rr = rbase + ii;
        d[ii] = fmaxf((float)cnt[(rr < N_NODES) ? rr : (N_NODES - 1)], 1.0f);
    }
    #pragma unroll
    for (int t = 0; t < 4; ++t) {
        int col = wc * 64 + t * 16 + r;     // D: col=lane&15, row=quad*4+reg
        float bb = canon[cbias + col];
        #pragma unroll
        for (int ii = 0; ii < 4; ++ii) {
            int rr = rbase + ii;
            if (rr < N_NODES) {
                float v = gacc[t][ii] / d[ii] + bb;
                if (dorelu) v = fmaxf(v, 0.f);
                xout[(size_t)rr * 128 + col] = f2bf(v);
            }
        }
    }
}

// ---------------- DistMult on bf16 x2: 8 lanes/edge, 8 edges/wave ----------------
__global__ void k_distmult8b(const ushort_t* __restrict__ x2, const float* __restrict__ canon,
                             const int* __restrict__ ei, const int* __restrict__ et,
                             const int* __restrict__ neg, float* __restrict__ outp,
                             float* __restrict__ partials) {
    __shared__ float srel[1536];                  // 12 rel x 128, 6 KB
    int tid = threadIdx.x;
    for (int i = tid; i < 1536; i += 256) srel[i] = canon[C_REL + i];
    __syncthreads();
    int lane = tid & 63;
    int g = lane >> 3;
    int l = lane & 7;
    int w = (blockIdx.x * blockDim.x + tid) >> 6;
    int nw = (DM_BLOCKS * 256) >> 6;
    float aL1 = 0.f, aL2 = 0.f, aA = 0.f;
    for (int gid = w; gid < N_GROUPS; gid += nw) {
        int e = gid * 8 + g;
        int h = ei[e], t = ei[N_EDGE + e], r = et[e], qn = neg[e];
        const ushort_t* ph = x2 + (size_t)h * 128 + l * 16;
        const ushort_t* pt = x2 + (size_t)t * 128 + l * 16;
        const ushort_t* pq = x2 + (size_t)qn * 128 + l * 16;
        const float*    pr = srel + r * 128 + l * 16;
        short8 h0 = *(const short8*)ph, h1 = *(const short8*)(ph + 8);
        short8 t0 = *(const short8*)pt, t1 = *(const short8*)(pt + 8);
        short8 q0 = *(const short8*)pq, q1 = *(const short8*)(pq + 8);
        float sp = 0.f, sn = 0.f;
        #pragma unroll
        for (int j = 0; j < 8; ++j) {
            float hv = bf2f(((const ushort_t*)&h0)[j]) * pr[j];
            sp += hv * bf2f(((const ushort_t*)&t0)[j]);
            sn += hv * bf2f(((const ushort_t*)&q0)[j]);
        }
        #pragma unroll
        for (int j = 0; j < 8; ++j) {
            float hv = bf2f(((const ushort_t*)&h1)[j]) * pr[8 + j];
            sp += hv * bf2f(((const ushort_t*)&t1)[j]);
            sn += hv * bf2f(((const ushort_t*)&q1)[j]);
        }
        sp += __shfl_down(sp, 4); sn += __shfl_down(sn, 4);
        sp += __shfl_down(sp, 2); sn += __shfl_down(sn, 2);
        sp += __shfl_down(sp, 1); sn += __shfl_down(sn, 1);
        if (l == 0) {
            outp[e] = sp;
            aL1 += softplus(-sp);
            aL2 += softplus(sn);
            aA  += (sp > sn) ? 1.0f : 0.0f;
        }
    }
    #pragma unroll
    for (int off = 32; off; off >>= 1) {
        aL1 += __shfl_down(aL1, off);
        aL2 += __shfl_down(aL2, off);
        aA  += __shfl_down(aA,  off);
    }
    __shared__ float s[3][4];
    int wl = tid >> 6;
    if (lane == 0) { s[0][wl] = aL1; s[1][wl] = aL2; s[2][wl] = aA; }
    __syncthreads();
    if (tid == 0) {
        float t0 = 0.f, t1 = 0.f, t2 = 0.f;
        for (int i = 0; i < 4; ++i) { t0 += s[0][i]; t1 += s[1][i]; t2 += s[2][i]; }
        partials[blockIdx.x * 3 + 0] = t0;
        partials[blockIdx.x * 3 + 1] = t1;
        partials[blockIdx.x * 3 + 2] = t2;
    }
}

__global__ void k_final(const float* __restrict__ partials, float* __restrict__ outp) {
    __shared__ float s[3][256];
    int tid = threadIdx.x;
    float t0 = 0.f, t1 = 0.f, t2 = 0.f;
    for (int i = tid; i < DM_BLOCKS; i += 256) {
        t0 += partials[i * 3 + 0];
        t1 += partials[i * 3 + 1];
        t2 += partials[i * 3 + 2];
    }
    s[0][tid] = t0; s[1][tid] = t1; s[2][tid] = t2;
    __syncthreads();
    for (int st = 128; st; st >>= 1) {
        if (tid < st) {
            s[0][tid] += s[0][tid + st];
            s[1][tid] += s[1][tid + st];
            s[2][tid] += s[2][tid + st];
        }
        __syncthreads();
    }
    if (tid == 0) {
        float inv = 1.0f / (float)N_EDGE;
        outp[N_EDGE]     = 0.5f * (s[0][0] * inv + s[1][0] * inv);
        outp[N_EDGE + 1] = s[2][0] * inv;
    }
}

extern "C" void kernel_launch(void* const* d_in, const int* in_sizes, int n_in,
                              void* d_out, int out_size, void* d_ws, size_t ws_size,
                              hipStream_t stream) {
    const void* emb    = d_in[0];
    const void* ebias  = d_in[1];
    const void* bases1 = d_in[2];
    const void* comp1  = d_in[3];
    const void* bias1  = d_in[4];
    const void* bases2 = d_in[5];
    const void* comp2  = d_in[6];
    const void* bias2  = d_in[7];
    const void* rel    = d_in[8];
    const int*  ei     = (const int*)d_in[9];
    const int*  et     = (const int*)d_in[10];
    const int*  neg    = (const int*)d_in[11];
    float*      outp   = (float*)d_out;

    char* ws = (char*)d_ws;
    size_t off = 0;
    auto alloc = [&](size_t bytes) { char* p = ws + off; off += (bytes + 255) & ~(size_t)255; return p; };
    int*          flag   = (int*)alloc(256);
    float*        canon  = (float*)alloc((size_t)C_TOTAL * 4);
    int*          cnt    = (int*)alloc((size_t)N_NODES * 4);
    int*          ptr    = (int*)alloc((size_t)(N_NODES + 1) * 4);
    int*          cursor = (int*)alloc((size_t)N_NODES * 4);
    int*          bsum   = (int*)alloc(SCAN_BLOCKS * 4);
    int*          boff   = (int*)alloc(64 * 4);
    ushort_t*     btK1   = (ushort_t*)alloc((size_t)128 * 512 * 2);
    ushort_t*     btK2   = (ushort_t*)alloc((size_t)128 * 512 * 2);
    float*        part   = (float*)alloc((size_t)DM_BLOCKS * 3 * 4);
    unsigned int* packed = (unsigned int*)alloc((size_t)N_EDGE * 4);
    ushort_t*     x      = (ushort_t*)alloc((size_t)N_NODES * 128 * 2);   // 12.8 MB
    ushort_t*     xb     = (ushort_t*)alloc((size_t)N_NODES * 128 * 2);   // 12.8 MB
    // total ~28 MB << ws_size

    k_prep<<<1, 256, 0, stream>>>((const ushort_t*)emb, flag, comp1, comp2, bias1, bias2,
                                  rel, ebias, canon);
    (void)hipMemsetAsync(cnt, 0, (size_t)N_NODES * 4, stream);
    k_cnt<<<N_EDGE / 256, 256, 0, stream>>>(ei, cnt);
    k_scan1<<<SCAN_BLOCKS, 1024, 0, stream>>>(cnt, ptr, bsum);
    k_scan2<<<1, 64, 0, stream>>>(bsum, boff);
    k_scan3<<<SCAN_BLOCKS, 1024, 0, stream>>>(ptr, cursor, boff);
    k_fill<<<N_EDGE / 256, 256, 0, stream>>>(ei, et, cursor, packed);
    k_init<<<512 + (N_NODES * 128 + 255) / 256, 256, 0, stream>>>(
        bases1, btK1, bases2, btK2, emb, canon, x, flag);

    int fgrid = (N_NODES + TILE_M - 1) / TILE_M;   // 1563

    // layer 1: xb <- bf16(relu( (gather(comp1 (x) x)) @ W1 / deg + bias1 ))
    k_fused<<<fgrid, 256, 0, stream>>>(x, ptr, packed, canon + C_COMP1, btK1, cnt,
                                       canon, xb, C_BIAS1, 1);
    // layer 2: x <- bf16( (gather(comp2 (x) xb)) @ W2 / deg + bias2 )
    k_fused<<<fgrid, 256, 0, stream>>>(xb, ptr, packed, canon + C_COMP2, btK2, cnt,
                                       canon, x, C_BIAS2, 0);

    // decode + loss
    k_distmult8b<<<DM_BLOCKS, 256, 0, stream>>>(x, canon, ei, et, neg, outp, part);
    k_final<<<1, 256, 0, stream>>>(part, outp);
}

// Round 5
// 331.887 us; speedup vs baseline: 1.0407x; 1.0407x over previous
//
#include <hip/hip_runtime.h>

typedef unsigned short ushort_t;
typedef __attribute__((ext_vector_type(8))) short short8;
typedef __attribute__((ext_vector_type(4))) short s16x4;
typedef __attribute__((ext_vector_type(4))) float f32x4;

#define N_NODES 50000
#define NBASE   4
#define N_EDGE  320000
#define DM_BLOCKS 2048
#define N_GROUPS (N_EDGE / 8)
#define SCAN_BLOCKS 49          // 49*1024 = 50176 >= 50000
#define LDSB_STRIDE 136         // 128 + 8 ushorts pad

// canonical fp32 small-tensor layout (element offsets)
#define C_COMP1 0
#define C_COMP2 100
#define C_BIAS1 200
#define C_BIAS2 328
#define C_REL   456
#define C_EBIAS 1992
#define C_TOTAL 2120

__device__ __forceinline__ float bf2f(ushort_t u) {
    union { unsigned int i; float f; } v; v.i = ((unsigned int)u) << 16; return v.f;
}
__device__ __forceinline__ ushort_t f2bf(float f) {
    union { float f; unsigned int i; } v; v.f = f;
    unsigned int u = v.i;
    u = (u + 0x7FFFu + ((u >> 16) & 1u)) >> 16;   // RNE
    return (ushort_t)u;
}
__device__ __forceinline__ float readf(const void* p, int i, int isbf) {
    return isbf ? bf2f(((const ushort_t*)p)[i]) : ((const float*)p)[i];
}
__device__ __forceinline__ float softplus(float x) {
    if (x > 20.f) return x;
    if (x < -20.f) return expf(x);
    return log1pf(expf(x));
}

// Fused: dtype-detect + canonicalize small tensors (block 0) + zero cnt & ticket (blocks >= 1).
__global__ void k_prep(const ushort_t* __restrict__ emb, int* __restrict__ flag,
                       const void* comp1, const void* comp2, const void* b1, const void* b2,
                       const void* rel, const void* eb, float* __restrict__ canon,
                       int* __restrict__ cntz, int* __restrict__ tick) {
    if (blockIdx.x > 0) {
        int i = (blockIdx.x - 1) * 256 + threadIdx.x;
        if (i < N_NODES) cntz[i] = 0;
        return;
    }
    __shared__ int cnt;
    if (threadIdx.x == 0) { cnt = 0; *tick = 0; }
    __syncthreads();
    int e = (emb[threadIdx.x] >> 7) & 0xFF;
    if (e >= 100 && e <= 126) atomicAdd(&cnt, 1);
    __syncthreads();
    if (threadIdx.x == 0) *flag = (cnt >= 200) ? 1 : 0;  // 1 = bf16 inputs
    __syncthreads();
    int isbf = (cnt >= 200) ? 1 : 0;
    for (int i = threadIdx.x; i < C_TOTAL; i += blockDim.x) {
        float v;
        if      (i < C_COMP2) v = readf(comp1, i - C_COMP1, isbf);
        else if (i < C_BIAS1) v = readf(comp2, i - C_COMP2, isbf);
        else if (i < C_BIAS2) v = readf(b1,    i - C_BIAS1, isbf);
        else if (i < C_REL)   v = readf(b2,    i - C_BIAS2, isbf);
        else if (i < C_EBIAS) v = readf(rel,   i - C_REL,   isbf);
        else                  v = readf(eb,    i - C_EBIAS, isbf);
        canon[i] = v;
    }
}

// Fused init: blocks [0,256)   -> repack bases1 -> btK1[o][b*128+i]
//             blocks [256,512) -> repack bases2 -> btK2
//             blocks [512, ..) -> x = bf16(relu(emb + ebias))
__global__ void k_init(const void* __restrict__ bases1, ushort_t* __restrict__ btK1,
                       const void* __restrict__ bases2, ushort_t* __restrict__ btK2,
                       const void* __restrict__ emb, const float* __restrict__ canon,
                       ushort_t* __restrict__ x, const int* __restrict__ flag) {
    int isbf = *flag;
    int bid = blockIdx.x;
    if (bid < 512) {
        const void* bases = (bid < 256) ? bases1 : bases2;
        ushort_t* btK = (bid < 256) ? btK1 : btK2;
        int idx = (bid & 255) * 256 + threadIdx.x;      // < 65536
        int b = idx >> 14, i = (idx >> 7) & 127, o = idx & 127;
        btK[(size_t)o * 512 + (b << 7) + i] = f2bf(readf(bases, idx, isbf));
    } else {
        int i = (bid - 512) * 256 + threadIdx.x;
        if (i < N_NODES * 128) {
            float v = readf(emb, i, isbf) + canon[C_EBIAS + (i & 127)];
            x[i] = f2bf(fmaxf(v, 0.f));
        }
    }
}

// ---------------- CSR build (dst-indexed) ----------------
__global__ void k_cnt(const int* __restrict__ ei, int* __restrict__ cnt) {
    int e = blockIdx.x * blockDim.x + threadIdx.x;
    if (e >= N_EDGE) return;
    atomicAdd(&cnt[ei[N_EDGE + e]], 1);
}

__global__ void k_scan1(const int* __restrict__ cnt, int* __restrict__ ptr,
                        int* __restrict__ bsum) {
    __shared__ int s[1024];
    int t = threadIdx.x;
    int i = blockIdx.x * 1024 + t;
    int v = (i < N_NODES) ? cnt[i] : 0;
    s[t] = v;
    __syncthreads();
    for (int off = 1; off < 1024; off <<= 1) {
        int u = (t >= off) ? s[t - off] : 0;
        __syncthreads();
        s[t] += u;
        __syncthreads();
    }
    if (i < N_NODES) ptr[i] = s[t] - v;
    if (t == 1023) bsum[blockIdx.x] = s[1023];
}

// scan3 derives its own block offset from bsum (masked wave reduction, 49 values)
__global__ void k_scan3(int* __restrict__ ptr, int* __restrict__ cursor,
                        const int* __restrict__ bsum) {
    __shared__ int sboff;
    int t = threadIdx.x;
    if (t < 64) {
        int v = (t < blockIdx.x) ? bsum[t] : 0;   // blockIdx.x <= 48 < 64
        #pragma unroll
        for (int off = 32; off; off >>= 1) v += __shfl_down(v, off);
        if (t == 0) sboff = v;
    }
    __syncthreads();
    int i = blockIdx.x * 1024 + t;
    if (i < N_NODES) {
        int p = ptr[i] + sboff;
        ptr[i] = p;
        cursor[i] = p;
    }
    if (blockIdx.x == 0 && t == 0) ptr[N_NODES] = N_EDGE;
}

__global__ void k_fill(const int* __restrict__ ei, const int* __restrict__ et,
                       int* __restrict__ cursor, unsigned int* __restrict__ packed) {
    int e = blockIdx.x * blockDim.x + threadIdx.x;
    if (e >= N_EDGE) return;
    int dst = ei[N_EDGE + e];
    int pos = atomicAdd(&cursor[dst], 1);
    packed[pos] = (unsigned int)(ei[e] & 0xFFFF) | ((unsigned int)et[e] << 16);
}

// ---------------- pre-projection aggregate (x-space gather) ----------------
// y[m, b*128+o] = sum_{e in CSR[m]} comp[r_e, b] * x[src_e, o]    (bf16 out)
// ONE NODE PER HALF-WAVE: 32 lanes x dwordx2 (8B = 4 cols) per edge row.
__global__ void k_agg2(const ushort_t* __restrict__ x, const int* __restrict__ ptr,
                       const unsigned int* __restrict__ packed, const float* __restrict__ compf,
                       ushort_t* __restrict__ y) {
    __shared__ __align__(16) float sc[100];
    int tid = threadIdx.x;                  // 256 = 4 waves = 8 half-waves -> 8 nodes/block
    for (int i = tid; i < 100; i += 256) sc[i] = compf[i];
    __syncthreads();
    int m = blockIdx.x * 8 + (tid >> 5);    // node for this half-wave
    int li = tid & 31;
    int c0 = li << 2;                       // this lane owns cols c0..c0+3
    int beg = ptr[m], end = ptr[m + 1];
    float acc[4][4];                        // [base][col]
    #pragma unroll
    for (int b = 0; b < 4; ++b)
        #pragma unroll
        for (int j = 0; j < 4; ++j) acc[b][j] = 0.f;

    int i = beg;
    for (; i + 4 <= end; i += 4) {
        unsigned int p0 = packed[i], p1 = packed[i + 1];
        unsigned int p2 = packed[i + 2], p3 = packed[i + 3];
        s16x4 w0 = *(const s16x4*)(x + (size_t)(p0 & 0xFFFFu) * 128 + c0);
        s16x4 w1 = *(const s16x4*)(x + (size_t)(p1 & 0xFFFFu) * 128 + c0);
        s16x4 w2 = *(const s16x4*)(x + (size_t)(p2 & 0xFFFFu) * 128 + c0);
        s16x4 w3 = *(const s16x4*)(x + (size_t)(p3 & 0xFFFFu) * 128 + c0);
        f32x4 cc0 = *(const f32x4*)(sc + (p0 >> 16) * 4);
        f32x4 cc1 = *(const f32x4*)(sc + (p1 >> 16) * 4);
        f32x4 cc2 = *(const f32x4*)(sc + (p2 >> 16) * 4);
        f32x4 cc3 = *(const f32x4*)(sc + (p3 >> 16) * 4);
        #pragma unroll
        for (int j = 0; j < 4; ++j) {
            float v = bf2f((ushort_t)((const short*)&w0)[j]);
            acc[0][j] += cc0[0] * v; acc[1][j] += cc0[1] * v;
            acc[2][j] += cc0[2] * v; acc[3][j] += cc0[3] * v;
        }
        #pragma unroll
        for (int j = 0; j < 4; ++j) {
            float v = bf2f((ushort_t)((const short*)&w1)[j]);
            acc[0][j] += cc1[0] * v; acc[1][j] += cc1[1] * v;
            acc[2][j] += cc1[2] * v; acc[3][j] += cc1[3] * v;
        }
        #pragma unroll
        for (int j = 0; j < 4; ++j) {
            float v = bf2f((ushort_t)((const short*)&w2)[j]);
            acc[0][j] += cc2[0] * v; acc[1][j] += cc2[1] * v;
            acc[2][j] += cc2[2] * v; acc[3][j] += cc2[3] * v;
        }
        #pragma unroll
        for (int j = 0; j < 4; ++j) {
            float v = bf2f((ushort_t)((const short*)&w3)[j]);
            acc[0][j] += cc3[0] * v; acc[1][j] += cc3[1] * v;
            acc[2][j] += cc3[2] * v; acc[3][j] += cc3[3] * v;
        }
    }
    for (; i < end; ++i) {
        unsigned int p0 = packed[i];
        s16x4 w0 = *(const s16x4*)(x + (size_t)(p0 & 0xFFFFu) * 128 + c0);
        f32x4 cc0 = *(const f32x4*)(sc + (p0 >> 16) * 4);
        #pragma unroll
        for (int j = 0; j < 4; ++j) {
            float v = bf2f((ushort_t)((const short*)&w0)[j]);
            acc[0][j] += cc0[0] * v; acc[1][j] += cc0[1] * v;
            acc[2][j] += cc0[2] * v; acc[3][j] += cc0[3] * v;
        }
    }
    // write y[m, b*128 + c0 .. c0+3] for b = 0..3 : 8B dwordx2 per base per lane
    ushort_t* yrow = y + (size_t)m * 512;
    #pragma unroll
    for (int b = 0; b < 4; ++b) {
        unsigned int lo = (unsigned int)f2bf(acc[b][0]) | ((unsigned int)f2bf(acc[b][1]) << 16);
        unsigned int hi = (unsigned int)f2bf(acc[b][2]) | ((unsigned int)f2bf(acc[b][3]) << 16);
        unsigned int* yp = (unsigned int*)(yrow + (b << 7) + c0);
        yp[0] = lo;
        yp[1] = hi;
    }
}

// ---------------- K=512 GEMM: xout = post(y @ W) ----------------
__global__ __launch_bounds__(256) void
k_gemm512(const ushort_t* __restrict__ y, const ushort_t* __restrict__ btK,
          const int* __restrict__ cnt, const float* __restrict__ canon,
          ushort_t* __restrict__ xout, int cbias, int dorelu) {
    __shared__ ushort_t bs[128 * LDSB_STRIDE];    // 34.8 KB
    int tid = threadIdx.x;
    int lane = tid & 63, w = tid >> 6;
    int r = lane & 15, q = lane >> 4;
    int m0 = blockIdx.x * 128;
    f32x4 acc[2][8] = {};
    int row0 = m0 + w * 32 + r;
    int row1 = row0 + 16;
    int cr0 = (row0 < N_NODES) ? row0 : (N_NODES - 1);
    int cr1 = (row1 < N_NODES) ? row1 : (N_NODES - 1);
    const ushort_t* ar0 = y + (size_t)cr0 * 512;
    const ushort_t* ar1 = y + (size_t)cr1 * 512;

    for (int c = 0; c < 4; ++c) {
        __syncthreads();
        {
            int o = tid >> 4;
            int j = (tid & 15) << 3;
            #pragma unroll
            for (int s = 0; s < 8; ++s, o += 16) {
                short8 v = *(const short8*)(btK + (size_t)o * 512 + c * 128 + j);
                *(short8*)(bs + o * LDSB_STRIDE + j) = v;
            }
        }
        __syncthreads();
        #pragma unroll
        for (int ksl = 0; ksl < 4; ++ksl) {
            int k0 = ksl * 32 + q * 8;
            short8 a0 = *(const short8*)(ar0 + c * 128 + k0);
            short8 a1 = *(const short8*)(ar1 + c * 128 + k0);
            #pragma unroll
            for (int t = 0; t < 8; ++t) {
                short8 b = *(const short8*)(bs + (t * 16 + r) * LDSB_STRIDE + k0);
                acc[0][t] = __builtin_amdgcn_mfma_f32_16x16x32_bf16(a0, b, acc[0][t], 0, 0, 0);
                acc[1][t] = __builtin_amdgcn_mfma_f32_16x16x32_bf16(a1, b, acc[1][t], 0, 0, 0);
            }
        }
    }
    #pragma unroll
    for (int i = 0; i < 2; ++i) {
        int rbase = m0 + w * 32 + i * 16 + (q << 2);
        float d[4];
        #pragma unroll
        for (int ii = 0; ii < 4; ++ii) {
            int rr = rbase + ii;
            d[ii] = fmaxf((float)cnt[(rr < N_NODES) ? rr : (N_NODES - 1)], 1.0f);
        }
        #pragma unroll
        for (int t = 0; t < 8; ++t) {
            int col = t * 16 + r;                 // D: col=lane&15, row=quad*4+reg
            float bb = canon[cbias + col];
            #pragma unroll
            for (int ii = 0; ii < 4; ++ii) {
                int rr = rbase + ii;
                if (rr < N_NODES) {
                    float v = acc[i][t][ii] / d[ii] + bb;
                    if (dorelu) v = fmaxf(v, 0.f);
                    xout[(size_t)rr * 128 + col] = f2bf(v);
                }
            }
        }
    }
}

// ---------------- DistMult + fused final reduction (last-block pattern) ----------------
__global__ void k_distmult8b(const ushort_t* __restrict__ x2, const float* __restrict__ canon,
                             const int* __restrict__ ei, const int* __restrict__ et,
                             const int* __restrict__ neg, float* __restrict__ outp,
                             float* __restrict__ partials, int* __restrict__ tick) {
    __shared__ float srel[1536];                  // 12 rel x 128, 6 KB
    int tid = threadIdx.x;
    for (int i = tid; i < 1536; i += 256) srel[i] = canon[C_REL + i];
    __syncthreads();
    int lane = tid & 63;
    int g = lane >> 3;
    int l = lane & 7;
    int w = (blockIdx.x * blockDim.x + tid) >> 6;
    int nw = (DM_BLOCKS * 256) >> 6;
    float aL1 = 0.f, aL2 = 0.f, aA = 0.f;
    for (int gid = w; gid < N_GROUPS; gid += nw) {
        int e = gid * 8 + g;
        int h = ei[e], t = ei[N_EDGE + e], r = et[e], qn = neg[e];
        const ushort_t* ph = x2 + (size_t)h * 128 + l * 16;
        const ushort_t* pt = x2 + (size_t)t * 128 + l * 16;
        const ushort_t* pq = x2 + (size_t)qn * 128 + l * 16;
        const float*    pr = srel + r * 128 + l * 16;
        short8 h0 = *(const short8*)ph, h1 = *(const short8*)(ph + 8);
        short8 t0 = *(const short8*)pt, t1 = *(const short8*)(pt + 8);
        short8 q0 = *(const short8*)pq, q1 = *(const short8*)(pq + 8);
        float sp = 0.f, sn = 0.f;
        #pragma unroll
        for (int j = 0; j < 8; ++j) {
            float hv = bf2f(((const ushort_t*)&h0)[j]) * pr[j];
            sp += hv * bf2f(((const ushort_t*)&t0)[j]);
            sn += hv * bf2f(((const ushort_t*)&q0)[j]);
        }
        #pragma unroll
        for (int j = 0; j < 8; ++j) {
            float hv = bf2f(((const ushort_t*)&h1)[j]) * pr[8 + j];
            sp += hv * bf2f(((const ushort_t*)&t1)[j]);
            sn += hv * bf2f(((const ushort_t*)&q1)[j]);
        }
        sp += __shfl_down(sp, 4); sn += __shfl_down(sn, 4);
        sp += __shfl_down(sp, 2); sn += __shfl_down(sn, 2);
        sp += __shfl_down(sp, 1); sn += __shfl_down(sn, 1);
        if (l == 0) {
            outp[e] = sp;
            aL1 += softplus(-sp);
            aL2 += softplus(sn);
            aA  += (sp > sn) ? 1.0f : 0.0f;
        }
    }
    #pragma unroll
    for (int off = 32; off; off >>= 1) {
        aL1 += __shfl_down(aL1, off);
        aL2 += __shfl_down(aL2, off);
        aA  += __shfl_down(aA,  off);
    }
    __shared__ float s[3][4];
    __shared__ int amlast;
    int wl = tid >> 6;
    if (lane == 0) { s[0][wl] = aL1; s[1][wl] = aL2; s[2][wl] = aA; }
    __syncthreads();
    if (tid == 0) {
        float t0 = 0.f, t1 = 0.f, t2 = 0.f;
        for (int i = 0; i < 4; ++i) { t0 += s[0][i]; t1 += s[1][i]; t2 += s[2][i]; }
        partials[blockIdx.x * 3 + 0] = t0;
        partials[blockIdx.x * 3 + 1] = t1;
        partials[blockIdx.x * 3 + 2] = t2;
        __threadfence();
        int t = atomicAdd(tick, 1);
        amlast = (t == DM_BLOCKS - 1) ? 1 : 0;
    }
    __syncthreads();
    if (amlast) {
        __threadfence();
        // identical reduction tree to the old k_final (deterministic)
        __shared__ float sf[3][256];
        float t0 = 0.f, t1 = 0.f, t2 = 0.f;
        for (int i = tid; i < DM_BLOCKS; i += 256) {
            t0 += partials[i * 3 + 0];
            t1 += partials[i * 3 + 1];
            t2 += partials[i * 3 + 2];
        }
        sf[0][tid] = t0; sf[1][tid] = t1; sf[2][tid] = t2;
        __syncthreads();
        for (int st = 128; st; st >>= 1) {
            if (tid < st) {
                sf[0][tid] += sf[0][tid + st];
                sf[1][tid] += sf[1][tid + st];
                sf[2][tid] += sf[2][tid + st];
            }
            __syncthreads();
        }
        if (tid == 0) {
            float inv = 1.0f / (float)N_EDGE;
            outp[N_EDGE]     = 0.5f * (sf[0][0] * inv + sf[1][0] * inv);
            outp[N_EDGE + 1] = sf[2][0] * inv;
        }
    }
}

extern "C" void kernel_launch(void* const* d_in, const int* in_sizes, int n_in,
                              void* d_out, int out_size, void* d_ws, size_t ws_size,
                              hipStream_t stream) {
    const void* emb    = d_in[0];
    const void* ebias  = d_in[1];
    const void* bases1 = d_in[2];
    const void* comp1  = d_in[3];
    const void* bias1  = d_in[4];
    const void* bases2 = d_in[5];
    const void* comp2  = d_in[6];
    const void* bias2  = d_in[7];
    const void* rel    = d_in[8];
    const int*  ei     = (const int*)d_in[9];
    const int*  et     = (const int*)d_in[10];
    const int*  neg    = (const int*)d_in[11];
    float*      outp   = (float*)d_out;

    char* ws = (char*)d_ws;
    size_t off = 0;
    auto alloc = [&](size_t bytes) { char* p = ws + off; off += (bytes + 255) & ~(size_t)255; return p; };
    int*          flag   = (int*)alloc(256);
    int*          tick   = (int*)alloc(256);
    float*        canon  = (float*)alloc((size_t)C_TOTAL * 4);
    int*          cnt    = (int*)alloc((size_t)N_NODES * 4);
    int*          ptr    = (int*)alloc((size_t)(N_NODES + 1) * 4);
    int*          cursor = (int*)alloc((size_t)N_NODES * 4);
    int*          bsum   = (int*)alloc(SCAN_BLOCKS * 4);
    ushort_t*     btK1   = (ushort_t*)alloc((size_t)128 * 512 * 2);
    ushort_t*     btK2   = (ushort_t*)alloc((size_t)128 * 512 * 2);
    float*        part   = (float*)alloc((size_t)DM_BLOCKS * 3 * 4);
    unsigned int* packed = (unsigned int*)alloc((size_t)N_EDGE * 4);
    ushort_t*     x      = (ushort_t*)alloc((size_t)N_NODES * 128 * 2);   // 12.8 MB
    ushort_t*     y      = (ushort_t*)alloc((size_t)N_NODES * 512 * 2);   // 51.2 MB

    // 11 dispatches (was 14): memset folded into k_prep, scan2 folded into scan3,
    // k_final folded into distmult (last-block ticket).
    k_prep<<<1 + 196, 256, 0, stream>>>((const ushort_t*)emb, flag, comp1, comp2, bias1,
                                        bias2, rel, ebias, canon, cnt, tick);
    k_cnt<<<N_EDGE / 256, 256, 0, stream>>>(ei, cnt);
    k_scan1<<<SCAN_BLOCKS, 1024, 0, stream>>>(cnt, ptr, bsum);
    k_scan3<<<SCAN_BLOCKS, 1024, 0, stream>>>(ptr, cursor, bsum);
    k_fill<<<N_EDGE / 256, 256, 0, stream>>>(ei, et, cursor, packed);
    k_init<<<512 + (N_NODES * 128 + 255) / 256, 256, 0, stream>>>(
        bases1, btK1, bases2, btK2, emb, canon, x, flag);

    int ggrid = (N_NODES + 127) / 128;   // 391

    // layer 1: y = gather(comp1 (x) x);  x <- bf16(relu(y@W1 / deg + bias1))
    k_agg2<<<N_NODES / 8, 256, 0, stream>>>(x, ptr, packed, canon + C_COMP1, y);
    k_gemm512<<<ggrid, 256, 0, stream>>>(y, btK1, cnt, canon, x, C_BIAS1, 1);

    // layer 2: y = gather(comp2 (x) x);  x <- bf16(y@W2 / deg + bias2)   (= x2)
    k_agg2<<<N_NODES / 8, 256, 0, stream>>>(x, ptr, packed, canon + C_COMP2, y);
    k_gemm512<<<ggrid, 256, 0, stream>>>(y, btK2, cnt, canon, x, C_BIAS2, 0);

    // decode + loss (+ fused final)
    k_distmult8b<<<DM_BLOCKS, 256, 0, stream>>>(x, canon, ei, et, neg, outp, part, tick);
}

// Round 6
// 268.767 us; speedup vs baseline: 1.2851x; 1.2349x over previous
//
#include <hip/hip_runtime.h>

typedef unsigned short ushort_t;
typedef __attribute__((ext_vector_type(8))) short short8;
typedef __attribute__((ext_vector_type(4))) short s16x4;
typedef __attribute__((ext_vector_type(4))) float f32x4;

#define N_NODES 50000
#define NBASE   4
#define N_EDGE  320000
#define DM_BLOCKS 2048
#define N_GROUPS (N_EDGE / 8)
#define SCAN_BLOCKS 49          // 49*1024 = 50176 >= 50000
#define LDSB_STRIDE 136         // 128 + 8 ushorts pad

// canonical fp32 small-tensor layout (element offsets)
#define C_COMP1 0
#define C_COMP2 100
#define C_BIAS1 200
#define C_BIAS2 328
#define C_REL   456
#define C_EBIAS 1992
#define C_TOTAL 2120

__device__ __forceinline__ float bf2f(ushort_t u) {
    union { unsigned int i; float f; } v; v.i = ((unsigned int)u) << 16; return v.f;
}
__device__ __forceinline__ ushort_t f2bf(float f) {
    union { float f; unsigned int i; } v; v.f = f;
    unsigned int u = v.i;
    u = (u + 0x7FFFu + ((u >> 16) & 1u)) >> 16;   // RNE
    return (ushort_t)u;
}
__device__ __forceinline__ float readf(const void* p, int i, int isbf) {
    return isbf ? bf2f(((const ushort_t*)p)[i]) : ((const float*)p)[i];
}
__device__ __forceinline__ float softplus(float x) {
    if (x > 20.f) return x;
    if (x < -20.f) return expf(x);
    return log1pf(expf(x));
}

// Fused: dtype-detect + canonicalize small tensors (block 0) + zero cnt (blocks >= 1).
// NOTE: no device-scope fences anywhere here — cheap.
__global__ void k_prep(const ushort_t* __restrict__ emb, int* __restrict__ flag,
                       const void* comp1, const void* comp2, const void* b1, const void* b2,
                       const void* rel, const void* eb, float* __restrict__ canon,
                       int* __restrict__ cntz) {
    if (blockIdx.x > 0) {
        int i = (blockIdx.x - 1) * 256 + threadIdx.x;
        if (i < N_NODES) cntz[i] = 0;
        return;
    }
    __shared__ int cnt;
    if (threadIdx.x == 0) cnt = 0;
    __syncthreads();
    int e = (emb[threadIdx.x] >> 7) & 0xFF;
    if (e >= 100 && e <= 126) atomicAdd(&cnt, 1);
    __syncthreads();
    if (threadIdx.x == 0) *flag = (cnt >= 200) ? 1 : 0;  // 1 = bf16 inputs
    __syncthreads();
    int isbf = (cnt >= 200) ? 1 : 0;
    for (int i = threadIdx.x; i < C_TOTAL; i += blockDim.x) {
        float v;
        if      (i < C_COMP2) v = readf(comp1, i - C_COMP1, isbf);
        else if (i < C_BIAS1) v = readf(comp2, i - C_COMP2, isbf);
        else if (i < C_BIAS2) v = readf(b1,    i - C_BIAS1, isbf);
        else if (i < C_REL)   v = readf(b2,    i - C_BIAS2, isbf);
        else if (i < C_EBIAS) v = readf(rel,   i - C_REL,   isbf);
        else                  v = readf(eb,    i - C_EBIAS, isbf);
        canon[i] = v;
    }
}

// Fused init: blocks [0,256)   -> repack bases1 -> btK1[o][b*128+i]
//             blocks [256,512) -> repack bases2 -> btK2
//             blocks [512, ..) -> x = bf16(relu(emb + ebias))
__global__ void k_init(const void* __restrict__ bases1, ushort_t* __restrict__ btK1,
                       const void* __restrict__ bases2, ushort_t* __restrict__ btK2,
                       const void* __restrict__ emb, const float* __restrict__ canon,
                       ushort_t* __restrict__ x, const int* __restrict__ flag) {
    int isbf = *flag;
    int bid = blockIdx.x;
    if (bid < 512) {
        const void* bases = (bid < 256) ? bases1 : bases2;
        ushort_t* btK = (bid < 256) ? btK1 : btK2;
        int idx = (bid & 255) * 256 + threadIdx.x;      // < 65536
        int b = idx >> 14, i = (idx >> 7) & 127, o = idx & 127;
        btK[(size_t)o * 512 + (b << 7) + i] = f2bf(readf(bases, idx, isbf));
    } else {
        int i = (bid - 512) * 256 + threadIdx.x;
        if (i < N_NODES * 128) {
            float v = readf(emb, i, isbf) + canon[C_EBIAS + (i & 127)];
            x[i] = f2bf(fmaxf(v, 0.f));
        }
    }
}

// ---------------- CSR build (dst-indexed) ----------------
__global__ void k_cnt(const int* __restrict__ ei, int* __restrict__ cnt) {
    int e = blockIdx.x * blockDim.x + threadIdx.x;
    if (e >= N_EDGE) return;
    atomicAdd(&cnt[ei[N_EDGE + e]], 1);
}

__global__ void k_scan1(const int* __restrict__ cnt, int* __restrict__ ptr,
                        int* __restrict__ bsum) {
    __shared__ int s[1024];
    int t = threadIdx.x;
    int i = blockIdx.x * 1024 + t;
    int v = (i < N_NODES) ? cnt[i] : 0;
    s[t] = v;
    __syncthreads();
    for (int off = 1; off < 1024; off <<= 1) {
        int u = (t >= off) ? s[t - off] : 0;
        __syncthreads();
        s[t] += u;
        __syncthreads();
    }
    if (i < N_NODES) ptr[i] = s[t] - v;
    if (t == 1023) bsum[blockIdx.x] = s[1023];
}

// scan3 derives its own block offset from bsum (masked wave reduction, 49 values)
__global__ void k_scan3(int* __restrict__ ptr, int* __restrict__ cursor,
                        const int* __restrict__ bsum) {
    __shared__ int sboff;
    int t = threadIdx.x;
    if (t < 64) {
        int v = (t < blockIdx.x) ? bsum[t] : 0;   // blockIdx.x <= 48 < 64
        #pragma unroll
        for (int off = 32; off; off >>= 1) v += __shfl_down(v, off);
        if (t == 0) sboff = v;
    }
    __syncthreads();
    int i = blockIdx.x * 1024 + t;
    if (i < N_NODES) {
        int p = ptr[i] + sboff;
        ptr[i] = p;
        cursor[i] = p;
    }
    if (blockIdx.x == 0 && t == 0) ptr[N_NODES] = N_EDGE;
}

__global__ void k_fill(const int* __restrict__ ei, const int* __restrict__ et,
                       int* __restrict__ cursor, unsigned int* __restrict__ packed) {
    int e = blockIdx.x * blockDim.x + threadIdx.x;
    if (e >= N_EDGE) return;
    int dst = ei[N_EDGE + e];
    int pos = atomicAdd(&cursor[dst], 1);
    packed[pos] = (unsigned int)(ei[e] & 0xFFFF) | ((unsigned int)et[e] << 16);
}

// ---------------- pre-projection aggregate (x-space gather) ----------------
// y[m, b*128+o] = sum_{e in CSR[m]} comp[r_e, b] * x[src_e, o]    (bf16 out)
// ONE NODE PER HALF-WAVE: 32 lanes x dwordx2 (8B = 4 cols) per edge row.
__global__ void k_agg2(const ushort_t* __restrict__ x, const int* __restrict__ ptr,
                       const unsigned int* __restrict__ packed, const float* __restrict__ compf,
                       ushort_t* __restrict__ y) {
    __shared__ __align__(16) float sc[100];
    int tid = threadIdx.x;                  // 256 = 4 waves = 8 half-waves -> 8 nodes/block
    for (int i = tid; i < 100; i += 256) sc[i] = compf[i];
    __syncthreads();
    int m = blockIdx.x * 8 + (tid >> 5);    // node for this half-wave
    int li = tid & 31;
    int c0 = li << 2;                       // this lane owns cols c0..c0+3
    int beg = ptr[m], end = ptr[m + 1];
    float acc[4][4];                        // [base][col]
    #pragma unroll
    for (int b = 0; b < 4; ++b)
        #pragma unroll
        for (int j = 0; j < 4; ++j) acc[b][j] = 0.f;

    int i = beg;
    for (; i + 4 <= end; i += 4) {
        unsigned int p0 = packed[i], p1 = packed[i + 1];
        unsigned int p2 = packed[i + 2], p3 = packed[i + 3];
        s16x4 w0 = *(const s16x4*)(x + (size_t)(p0 & 0xFFFFu) * 128 + c0);
        s16x4 w1 = *(const s16x4*)(x + (size_t)(p1 & 0xFFFFu) * 128 + c0);
        s16x4 w2 = *(const s16x4*)(x + (size_t)(p2 & 0xFFFFu) * 128 + c0);
        s16x4 w3 = *(const s16x4*)(x + (size_t)(p3 & 0xFFFFu) * 128 + c0);
        f32x4 cc0 = *(const f32x4*)(sc + (p0 >> 16) * 4);
        f32x4 cc1 = *(const f32x4*)(sc + (p1 >> 16) * 4);
        f32x4 cc2 = *(const f32x4*)(sc + (p2 >> 16) * 4);
        f32x4 cc3 = *(const f32x4*)(sc + (p3 >> 16) * 4);
        #pragma unroll
        for (int j = 0; j < 4; ++j) {
            float v = bf2f((ushort_t)((const short*)&w0)[j]);
            acc[0][j] += cc0[0] * v; acc[1][j] += cc0[1] * v;
            acc[2][j] += cc0[2] * v; acc[3][j] += cc0[3] * v;
        }
        #pragma unroll
        for (int j = 0; j < 4; ++j) {
            float v = bf2f((ushort_t)((const short*)&w1)[j]);
            acc[0][j] += cc1[0] * v; acc[1][j] += cc1[1] * v;
            acc[2][j] += cc1[2] * v; acc[3][j] += cc1[3] * v;
        }
        #pragma unroll
        for (int j = 0; j < 4; ++j) {
            float v = bf2f((ushort_t)((const short*)&w2)[j]);
            acc[0][j] += cc2[0] * v; acc[1][j] += cc2[1] * v;
            acc[2][j] += cc2[2] * v; acc[3][j] += cc2[3] * v;
        }
        #pragma unroll
        for (int j = 0; j < 4; ++j) {
            float v = bf2f((ushort_t)((const short*)&w3)[j]);
            acc[0][j] += cc3[0] * v; acc[1][j] += cc3[1] * v;
            acc[2][j] += cc3[2] * v; acc[3][j] += cc3[3] * v;
        }
    }
    for (; i < end; ++i) {
        unsigned int p0 = packed[i];
        s16x4 w0 = *(const s16x4*)(x + (size_t)(p0 & 0xFFFFu) * 128 + c0);
        f32x4 cc0 = *(const f32x4*)(sc + (p0 >> 16) * 4);
        #pragma unroll
        for (int j = 0; j < 4; ++j) {
            float v = bf2f((ushort_t)((const short*)&w0)[j]);
            acc[0][j] += cc0[0] * v; acc[1][j] += cc0[1] * v;
            acc[2][j] += cc0[2] * v; acc[3][j] += cc0[3] * v;
        }
    }
    // write y[m, b*128 + c0 .. c0+3] for b = 0..3 : 8B dwordx2 per base per lane
    ushort_t* yrow = y + (size_t)m * 512;
    #pragma unroll
    for (int b = 0; b < 4; ++b) {
        unsigned int lo = (unsigned int)f2bf(acc[b][0]) | ((unsigned int)f2bf(acc[b][1]) << 16);
        unsigned int hi = (unsigned int)f2bf(acc[b][2]) | ((unsigned int)f2bf(acc[b][3]) << 16);
        unsigned int* yp = (unsigned int*)(yrow + (b << 7) + c0);
        yp[0] = lo;
        yp[1] = hi;
    }
}

// ---------------- K=512 GEMM: xout = post(y @ W) ----------------
__global__ __launch_bounds__(256) void
k_gemm512(const ushort_t* __restrict__ y, const ushort_t* __restrict__ btK,
          const int* __restrict__ cnt, const float* __restrict__ canon,
          ushort_t* __restrict__ xout, int cbias, int dorelu) {
    __shared__ ushort_t bs[128 * LDSB_STRIDE];    // 34.8 KB
    int tid = threadIdx.x;
    int lane = tid & 63, w = tid >> 6;
    int r = lane & 15, q = lane >> 4;
    int m0 = blockIdx.x * 128;
    f32x4 acc[2][8] = {};
    int row0 = m0 + w * 32 + r;
    int row1 = row0 + 16;
    int cr0 = (row0 < N_NODES) ? row0 : (N_NODES - 1);
    int cr1 = (row1 < N_NODES) ? row1 : (N_NODES - 1);
    const ushort_t* ar0 = y + (size_t)cr0 * 512;
    const ushort_t* ar1 = y + (size_t)cr1 * 512;

    for (int c = 0; c < 4; ++c) {
        __syncthreads();
        {
            int o = tid >> 4;
            int j = (tid & 15) << 3;
            #pragma unroll
            for (int s = 0; s < 8; ++s, o += 16) {
                short8 v = *(const short8*)(btK + (size_t)o * 512 + c * 128 + j);
                *(short8*)(bs + o * LDSB_STRIDE + j) = v;
            }
        }
        __syncthreads();
        #pragma unroll
        for (int ksl = 0; ksl < 4; ++ksl) {
            int k0 = ksl * 32 + q * 8;
            short8 a0 = *(const short8*)(ar0 + c * 128 + k0);
            short8 a1 = *(const short8*)(ar1 + c * 128 + k0);
            #pragma unroll
            for (int t = 0; t < 8; ++t) {
                short8 b = *(const short8*)(bs + (t * 16 + r) * LDSB_STRIDE + k0);
                acc[0][t] = __builtin_amdgcn_mfma_f32_16x16x32_bf16(a0, b, acc[0][t], 0, 0, 0);
                acc[1][t] = __builtin_amdgcn_mfma_f32_16x16x32_bf16(a1, b, acc[1][t], 0, 0, 0);
            }
        }
    }
    #pragma unroll
    for (int i = 0; i < 2; ++i) {
        int rbase = m0 + w * 32 + i * 16 + (q << 2);
        float d[4];
        #pragma unroll
        for (int ii = 0; ii < 4; ++ii) {
            int rr = rbase + ii;
            d[ii] = fmaxf((float)cnt[(rr < N_NODES) ? rr : (N_NODES - 1)], 1.0f);
        }
        #pragma unroll
        for (int t = 0; t < 8; ++t) {
            int col = t * 16 + r;                 // D: col=lane&15, row=quad*4+reg
            float bb = canon[cbias + col];
            #pragma unroll
            for (int ii = 0; ii < 4; ++ii) {
                int rr = rbase + ii;
                if (rr < N_NODES) {
                    float v = acc[i][t][ii] / d[ii] + bb;
                    if (dorelu) v = fmaxf(v, 0.f);
                    xout[(size_t)rr * 128 + col] = f2bf(v);
                }
            }
        }
    }
}

// ---------------- DistMult on bf16 x2: 8 lanes/edge, 8 edges/wave ----------------
// NO device-scope fences/atomics here (R5 lesson: 2048 per-block release fences
// flushed XCD L2 under the gather working set, 44us -> 102us).
__global__ void k_distmult8b(const ushort_t* __restrict__ x2, const float* __restrict__ canon,
                             const int* __restrict__ ei, const int* __restrict__ et,
                             const int* __restrict__ neg, float* __restrict__ outp,
                             float* __restrict__ partials) {
    __shared__ float srel[1536];                  // 12 rel x 128, 6 KB
    int tid = threadIdx.x;
    for (int i = tid; i < 1536; i += 256) srel[i] = canon[C_REL + i];
    __syncthreads();
    int lane = tid & 63;
    int g = lane >> 3;
    int l = lane & 7;
    int w = (blockIdx.x * blockDim.x + tid) >> 6;
    int nw = (DM_BLOCKS * 256) >> 6;
    float aL1 = 0.f, aL2 = 0.f, aA = 0.f;
    for (int gid = w; gid < N_GROUPS; gid += nw) {
        int e = gid * 8 + g;
        int h = ei[e], t = ei[N_EDGE + e], r = et[e], qn = neg[e];
        const ushort_t* ph = x2 + (size_t)h * 128 + l * 16;
        const ushort_t* pt = x2 + (size_t)t * 128 + l * 16;
        const ushort_t* pq = x2 + (size_t)qn * 128 + l * 16;
        const float*    pr = srel + r * 128 + l * 16;
        short8 h0 = *(const short8*)ph, h1 = *(const short8*)(ph + 8);
        short8 t0 = *(const short8*)pt, t1 = *(const short8*)(pt + 8);
        short8 q0 = *(const short8*)pq, q1 = *(const short8*)(pq + 8);
        float sp = 0.f, sn = 0.f;
        #pragma unroll
        for (int j = 0; j < 8; ++j) {
            float hv = bf2f(((const ushort_t*)&h0)[j]) * pr[j];
            sp += hv * bf2f(((const ushort_t*)&t0)[j]);
            sn += hv * bf2f(((const ushort_t*)&q0)[j]);
        }
        #pragma unroll
        for (int j = 0; j < 8; ++j) {
            float hv = bf2f(((const ushort_t*)&h1)[j]) * pr[8 + j];
            sp += hv * bf2f(((const ushort_t*)&t1)[j]);
            sn += hv * bf2f(((const ushort_t*)&q1)[j]);
        }
        sp += __shfl_down(sp, 4); sn += __shfl_down(sn, 4);
        sp += __shfl_down(sp, 2); sn += __shfl_down(sn, 2);
        sp += __shfl_down(sp, 1); sn += __shfl_down(sn, 1);
        if (l == 0) {
            outp[e] = sp;
            aL1 += softplus(-sp);
            aL2 += softplus(sn);
            aA  += (sp > sn) ? 1.0f : 0.0f;
        }
    }
    #pragma unroll
    for (int off = 32; off; off >>= 1) {
        aL1 += __shfl_down(aL1, off);
        aL2 += __shfl_down(aL2, off);
        aA  += __shfl_down(aA,  off);
    }
    __shared__ float s[3][4];
    int wl = tid >> 6;
    if (lane == 0) { s[0][wl] = aL1; s[1][wl] = aL2; s[2][wl] = aA; }
    __syncthreads();
    if (tid == 0) {
        float t0 = 0.f, t1 = 0.f, t2 = 0.f;
        for (int i = 0; i < 4; ++i) { t0 += s[0][i]; t1 += s[1][i]; t2 += s[2][i]; }
        partials[blockIdx.x * 3 + 0] = t0;
        partials[blockIdx.x * 3 + 1] = t1;
        partials[blockIdx.x * 3 + 2] = t2;
    }
}

__global__ void k_final(const float* __restrict__ partials, float* __restrict__ outp) {
    __shared__ float s[3][256];
    int tid = threadIdx.x;
    float t0 = 0.f, t1 = 0.f, t2 = 0.f;
    for (int i = tid; i < DM_BLOCKS; i += 256) {
        t0 += partials[i * 3 + 0];
        t1 += partials[i * 3 + 1];
        t2 += partials[i * 3 + 2];
    }
    s[0][tid] = t0; s[1][tid] = t1; s[2][tid] = t2;
    __syncthreads();
    for (int st = 128; st; st >>= 1) {
        if (tid < st) {
            s[0][tid] += s[0][tid + st];
            s[1][tid] += s[1][tid + st];
            s[2][tid] += s[2][tid + st];
        }
        __syncthreads();
    }
    if (tid == 0) {
        float inv = 1.0f / (float)N_EDGE;
        outp[N_EDGE]     = 0.5f * (s[0][0] * inv + s[1][0] * inv);
        outp[N_EDGE + 1] = s[2][0] * inv;
    }
}

extern "C" void kernel_launch(void* const* d_in, const int* in_sizes, int n_in,
                              void* d_out, int out_size, void* d_ws, size_t ws_size,
                              hipStream_t stream) {
    const void* emb    = d_in[0];
    const void* ebias  = d_in[1];
    const void* bases1 = d_in[2];
    const void* comp1  = d_in[3];
    const void* bias1  = d_in[4];
    const void* bases2 = d_in[5];
    const void* comp2  = d_in[6];
    const void* bias2  = d_in[7];
    const void* rel    = d_in[8];
    const int*  ei     = (const int*)d_in[9];
    const int*  et     = (const int*)d_in[10];
    const int*  neg    = (const int*)d_in[11];
    float*      outp   = (float*)d_out;

    char* ws = (char*)d_ws;
    size_t off = 0;
    auto alloc = [&](size_t bytes) { char* p = ws + off; off += (bytes + 255) & ~(size_t)255; return p; };
    int*          flag   = (int*)alloc(256);
    float*        canon  = (float*)alloc((size_t)C_TOTAL * 4);
    int*          cnt    = (int*)alloc((size_t)N_NODES * 4);
    int*          ptr    = (int*)alloc((size_t)(N_NODES + 1) * 4);
    int*          cursor = (int*)alloc((size_t)N_NODES * 4);
    int*          bsum   = (int*)alloc(SCAN_BLOCKS * 4);
    ushort_t*     btK1   = (ushort_t*)alloc((size_t)128 * 512 * 2);
    ushort_t*     btK2   = (ushort_t*)alloc((size_t)128 * 512 * 2);
    float*        part   = (float*)alloc((size_t)DM_BLOCKS * 3 * 4);
    unsigned int* packed = (unsigned int*)alloc((size_t)N_EDGE * 4);
    ushort_t*     x      = (ushort_t*)alloc((size_t)N_NODES * 128 * 2);   // 12.8 MB
    ushort_t*     y      = (ushort_t*)alloc((size_t)N_NODES * 512 * 2);   // 51.2 MB

    // 12 dispatches: memset folded into k_prep, scan2 folded into scan3;
    // distmult/final kept SEPARATE (R5 lesson).
    k_prep<<<1 + 196, 256, 0, stream>>>((const ushort_t*)emb, flag, comp1, comp2, bias1,
                                        bias2, rel, ebias, canon, cnt);
    k_cnt<<<N_EDGE / 256, 256, 0, stream>>>(ei, cnt);
    k_scan1<<<SCAN_BLOCKS, 1024, 0, stream>>>(cnt, ptr, bsum);
    k_scan3<<<SCAN_BLOCKS, 1024, 0, stream>>>(ptr, cursor, bsum);
    k_fill<<<N_EDGE / 256, 256, 0, stream>>>(ei, et, cursor, packed);
    k_init<<<512 + (N_NODES * 128 + 255) / 256, 256, 0, stream>>>(
        bases1, btK1, bases2, btK2, emb, canon, x, flag);

    int ggrid = (N_NODES + 127) / 128;   // 391

    // layer 1: y = gather(comp1 (x) x);  x <- bf16(relu(y@W1 / deg + bias1))
    k_agg2<<<N_NODES / 8, 256, 0, stream>>>(x, ptr, packed, canon + C_COMP1, y);
    k_gemm512<<<ggrid, 256, 0, stream>>>(y, btK1, cnt, canon, x, C_BIAS1, 1);

    // layer 2: y = gather(comp2 (x) x);  x <- bf16(y@W2 / deg + bias2)   (= x2)
    k_agg2<<<N_NODES / 8, 256, 0, stream>>>(x, ptr, packed, canon + C_COMP2, y);
    k_gemm512<<<ggrid, 256, 0, stream>>>(y, btK2, cnt, canon, x, C_BIAS2, 0);

    // decode + loss
    k_distmult8b<<<DM_BLOCKS, 256, 0, stream>>>(x, canon, ei, et, neg, outp, part);
    k_final<<<1, 256, 0, stream>>>(part, outp);
}

// Round 7
// 264.696 us; speedup vs baseline: 1.3049x; 1.0154x over previous
//
#include <hip/hip_runtime.h>

typedef unsigned short ushort_t;
typedef __attribute__((ext_vector_type(8))) short short8;
typedef __attribute__((ext_vector_type(4))) short s16x4;
typedef __attribute__((ext_vector_type(4))) float f32x4;

#define N_NODES 50000
#define NBASE   4
#define N_EDGE  320000
#define DM_BLOCKS 2048
#define N_GROUPS (N_EDGE / 8)
#define SCAN_BLOCKS 49          // 49*1024 = 50176 >= 50000
#define LDSB_STRIDE 136         // 128 + 8 ushorts pad
#define XOCT_BLOCKS 3125        // (50000*128/8)/256
#define CNT_BLOCKS  1250        // 320000/256

// canonical fp32 small-tensor layout (element offsets)
#define C_COMP1 0
#define C_COMP2 100
#define C_BIAS1 200
#define C_BIAS2 328
#define C_REL   456
#define C_EBIAS 1992
#define C_TOTAL 2120

__device__ __forceinline__ float bf2f(ushort_t u) {
    union { unsigned int i; float f; } v; v.i = ((unsigned int)u) << 16; return v.f;
}
__device__ __forceinline__ ushort_t f2bf(float f) {
    union { float f; unsigned int i; } v; v.f = f;
    unsigned int u = v.i;
    u = (u + 0x7FFFu + ((u >> 16) & 1u)) >> 16;   // RNE
    return (ushort_t)u;
}
__device__ __forceinline__ float readf(const void* p, int i, int isbf) {
    return isbf ? bf2f(((const ushort_t*)p)[i]) : ((const float*)p)[i];
}
__device__ __forceinline__ float softplus(float x) {
    if (x > 20.f) return x;
    if (x < -20.f) return expf(x);
    return log1pf(expf(x));
}

// Fused: dtype-detect + canonicalize small tensors (block 0) + zero cnt (blocks >= 1).
// NOTE: no device-scope fences anywhere here — cheap.
__global__ void k_prep(const ushort_t* __restrict__ emb, int* __restrict__ flag,
                       const void* comp1, const void* comp2, const void* b1, const void* b2,
                       const void* rel, const void* eb, float* __restrict__ canon,
                       int* __restrict__ cntz) {
    if (blockIdx.x > 0) {
        int i = (blockIdx.x - 1) * 256 + threadIdx.x;
        if (i < N_NODES) cntz[i] = 0;
        return;
    }
    __shared__ int cnt;
    if (threadIdx.x == 0) cnt = 0;
    __syncthreads();
    int e = (emb[threadIdx.x] >> 7) & 0xFF;
    if (e >= 100 && e <= 126) atomicAdd(&cnt, 1);
    __syncthreads();
    if (threadIdx.x == 0) *flag = (cnt >= 200) ? 1 : 0;  // 1 = bf16 inputs
    __syncthreads();
    int isbf = (cnt >= 200) ? 1 : 0;
    for (int i = threadIdx.x; i < C_TOTAL; i += blockDim.x) {
        float v;
        if      (i < C_COMP2) v = readf(comp1, i - C_COMP1, isbf);
        else if (i < C_BIAS1) v = readf(comp2, i - C_COMP2, isbf);
        else if (i < C_BIAS2) v = readf(b1,    i - C_BIAS1, isbf);
        else if (i < C_REL)   v = readf(b2,    i - C_BIAS2, isbf);
        else if (i < C_EBIAS) v = readf(rel,   i - C_REL,   isbf);
        else                  v = readf(eb,    i - C_EBIAS, isbf);
        canon[i] = v;
    }
}

// Fused init: blocks [0,256)        -> repack bases1 -> btK1[o][b*128+i]
//             blocks [256,512)      -> repack bases2 -> btK2
//             blocks [512,512+3125) -> x = bf16(relu(emb + ebias)), 8 elems/thread (16B ld/st)
//             blocks [512+3125,..)  -> edge-count histogram (independent; cnt zeroed by k_prep)
__global__ void k_init(const void* __restrict__ bases1, ushort_t* __restrict__ btK1,
                       const void* __restrict__ bases2, ushort_t* __restrict__ btK2,
                       const void* __restrict__ emb, const float* __restrict__ canon,
                       ushort_t* __restrict__ x, const int* __restrict__ flag,
                       const int* __restrict__ ei, int* __restrict__ cnt) {
    int bid = blockIdx.x;
    if (bid < 512) {
        int isbf = *flag;
        const void* bases = (bid < 256) ? bases1 : bases2;
        ushort_t* btK = (bid < 256) ? btK1 : btK2;
        int idx = (bid & 255) * 256 + threadIdx.x;      // < 65536
        int b = idx >> 14, i = (idx >> 7) & 127, o = idx & 127;
        btK[(size_t)o * 512 + (b << 7) + i] = f2bf(readf(bases, idx, isbf));
    } else if (bid < 512 + XOCT_BLOCKS) {
        int isbf = *flag;
        int base = ((bid - 512) * 256 + threadIdx.x) * 8;   // < 6,400,000, 16B aligned
        int col = base & 127;
        short8 out;
        if (isbf) {
            short8 v = *(const short8*)((const ushort_t*)emb + base);
            #pragma unroll
            for (int j = 0; j < 8; ++j) {
                float f = bf2f((ushort_t)v[j]) + canon[C_EBIAS + col + j];
                out[j] = (short)f2bf(fmaxf(f, 0.f));
            }
        } else {
            const float* ef = (const float*)emb + base;
            f32x4 v0 = *(const f32x4*)ef;
            f32x4 v1 = *(const f32x4*)(ef + 4);
            #pragma unroll
            for (int j = 0; j < 4; ++j) {
                float f = v0[j] + canon[C_EBIAS + col + j];
                out[j] = (short)f2bf(fmaxf(f, 0.f));
            }
            #pragma unroll
            for (int j = 0; j < 4; ++j) {
                float f = v1[j] + canon[C_EBIAS + col + 4 + j];
                out[4 + j] = (short)f2bf(fmaxf(f, 0.f));
            }
        }
        *(short8*)(x + base) = out;
    } else {
        int e = (bid - 512 - XOCT_BLOCKS) * 256 + threadIdx.x;   // < 320,000 exact
        atomicAdd(&cnt[ei[N_EDGE + e]], 1);
    }
}

// ---------------- CSR build (dst-indexed) ----------------
__global__ void k_scan1(const int* __restrict__ cnt, int* __restrict__ ptr,
                        int* __restrict__ bsum) {
    __shared__ int s[1024];
    int t = threadIdx.x;
    int i = blockIdx.x * 1024 + t;
    int v = (i < N_NODES) ? cnt[i] : 0;
    s[t] = v;
    __syncthreads();
    for (int off = 1; off < 1024; off <<= 1) {
        int u = (t >= off) ? s[t - off] : 0;
        __syncthreads();
        s[t] += u;
        __syncthreads();
    }
    if (i < N_NODES) ptr[i] = s[t] - v;
    if (t == 1023) bsum[blockIdx.x] = s[1023];
}

// scan3 derives its own block offset from bsum (masked wave reduction, 49 values)
__global__ void k_scan3(int* __restrict__ ptr, int* __restrict__ cursor,
                        const int* __restrict__ bsum) {
    __shared__ int sboff;
    int t = threadIdx.x;
    if (t < 64) {
        int v = (t < blockIdx.x) ? bsum[t] : 0;   // blockIdx.x <= 48 < 64
        #pragma unroll
        for (int off = 32; off; off >>= 1) v += __shfl_down(v, off);
        if (t == 0) sboff = v;
    }
    __syncthreads();
    int i = blockIdx.x * 1024 + t;
    if (i < N_NODES) {
        int p = ptr[i] + sboff;
        ptr[i] = p;
        cursor[i] = p;
    }
    if (blockIdx.x == 0 && t == 0) ptr[N_NODES] = N_EDGE;
}

__global__ void k_fill(const int* __restrict__ ei, const int* __restrict__ et,
                       int* __restrict__ cursor, unsigned int* __restrict__ packed) {
    int e = blockIdx.x * blockDim.x + threadIdx.x;
    if (e >= N_EDGE) return;
    int dst = ei[N_EDGE + e];
    int pos = atomicAdd(&cursor[dst], 1);
    packed[pos] = (unsigned int)(ei[e] & 0xFFFF) | ((unsigned int)et[e] << 16);
}

// ---------------- pre-projection aggregate (x-space gather) ----------------
// y[m, b*128+o] = sum_{e in CSR[m]} comp[r_e, b] * x[src_e, o]    (bf16 out)
// ONE NODE PER HALF-WAVE: 32 lanes x dwordx2 (8B = 4 cols) per edge row.
__global__ void k_agg2(const ushort_t* __restrict__ x, const int* __restrict__ ptr,
                       const unsigned int* __restrict__ packed, const float* __restrict__ compf,
                       ushort_t* __restrict__ y) {
    __shared__ __align__(16) float sc[100];
    int tid = threadIdx.x;                  // 256 = 4 waves = 8 half-waves -> 8 nodes/block
    for (int i = tid; i < 100; i += 256) sc[i] = compf[i];
    __syncthreads();
    int m = blockIdx.x * 8 + (tid >> 5);    // node for this half-wave
    int li = tid & 31;
    int c0 = li << 2;                       // this lane owns cols c0..c0+3
    int beg = ptr[m], end = ptr[m + 1];
    float acc[4][4];                        // [base][col]
    #pragma unroll
    for (int b = 0; b < 4; ++b)
        #pragma unroll
        for (int j = 0; j < 4; ++j) acc[b][j] = 0.f;

    int i = beg;
    for (; i + 4 <= end; i += 4) {
        unsigned int p0 = packed[i], p1 = packed[i + 1];
        unsigned int p2 = packed[i + 2], p3 = packed[i + 3];
        s16x4 w0 = *(const s16x4*)(x + (size_t)(p0 & 0xFFFFu) * 128 + c0);
        s16x4 w1 = *(const s16x4*)(x + (size_t)(p1 & 0xFFFFu) * 128 + c0);
        s16x4 w2 = *(const s16x4*)(x + (size_t)(p2 & 0xFFFFu) * 128 + c0);
        s16x4 w3 = *(const s16x4*)(x + (size_t)(p3 & 0xFFFFu) * 128 + c0);
        f32x4 cc0 = *(const f32x4*)(sc + (p0 >> 16) * 4);
        f32x4 cc1 = *(const f32x4*)(sc + (p1 >> 16) * 4);
        f32x4 cc2 = *(const f32x4*)(sc + (p2 >> 16) * 4);
        f32x4 cc3 = *(const f32x4*)(sc + (p3 >> 16) * 4);
        #pragma unroll
        for (int j = 0; j < 4; ++j) {
            float v = bf2f((ushort_t)((const short*)&w0)[j]);
            acc[0][j] += cc0[0] * v; acc[1][j] += cc0[1] * v;
            acc[2][j] += cc0[2] * v; acc[3][j] += cc0[3] * v;
        }
        #pragma unroll
        for (int j = 0; j < 4; ++j) {
            float v = bf2f((ushort_t)((const short*)&w1)[j]);
            acc[0][j] += cc1[0] * v; acc[1][j] += cc1[1] * v;
            acc[2][j] += cc1[2] * v; acc[3][j] += cc1[3] * v;
        }
        #pragma unroll
        for (int j = 0; j < 4; ++j) {
            float v = bf2f((ushort_t)((const short*)&w2)[j]);
            acc[0][j] += cc2[0] * v; acc[1][j] += cc2[1] * v;
            acc[2][j] += cc2[2] * v; acc[3][j] += cc2[3] * v;
        }
        #pragma unroll
        for (int j = 0; j < 4; ++j) {
            float v = bf2f((ushort_t)((const short*)&w3)[j]);
            acc[0][j] += cc3[0] * v; acc[1][j] += cc3[1] * v;
            acc[2][j] += cc3[2] * v; acc[3][j] += cc3[3] * v;
        }
    }
    for (; i < end; ++i) {
        unsigned int p0 = packed[i];
        s16x4 w0 = *(const s16x4*)(x + (size_t)(p0 & 0xFFFFu) * 128 + c0);
        f32x4 cc0 = *(const f32x4*)(sc + (p0 >> 16) * 4);
        #pragma unroll
        for (int j = 0; j < 4; ++j) {
            float v = bf2f((ushort_t)((const short*)&w0)[j]);
            acc[0][j] += cc0[0] * v; acc[1][j] += cc0[1] * v;
            acc[2][j] += cc0[2] * v; acc[3][j] += cc0[3] * v;
        }
    }
    // write y[m, b*128 + c0 .. c0+3] for b = 0..3 : 8B dwordx2 per base per lane
    ushort_t* yrow = y + (size_t)m * 512;
    #pragma unroll
    for (int b = 0; b < 4; ++b) {
        unsigned int lo = (unsigned int)f2bf(acc[b][0]) | ((unsigned int)f2bf(acc[b][1]) << 16);
        unsigned int hi = (unsigned int)f2bf(acc[b][2]) | ((unsigned int)f2bf(acc[b][3]) << 16);
        unsigned int* yp = (unsigned int*)(yrow + (b << 7) + c0);
        yp[0] = lo;
        yp[1] = hi;
    }
}

// ---------------- K=512 GEMM: xout = post(y @ W) ----------------
__global__ __launch_bounds__(256) void
k_gemm512(const ushort_t* __restrict__ y, const ushort_t* __restrict__ btK,
          const int* __restrict__ cnt, const float* __restrict__ canon,
          ushort_t* __restrict__ xout, int cbias, int dorelu) {
    __shared__ ushort_t bs[128 * LDSB_STRIDE];    // 34.8 KB
    int tid = threadIdx.x;
    int lane = tid & 63, w = tid >> 6;
    int r = lane & 15, q = lane >> 4;
    int m0 = blockIdx.x * 128;
    f32x4 acc[2][8] = {};
    int row0 = m0 + w * 32 + r;
    int row1 = row0 + 16;
    int cr0 = (row0 < N_NODES) ? row0 : (N_NODES - 1);
    int cr1 = (row1 < N_NODES) ? row1 : (N_NODES - 1);
    const ushort_t* ar0 = y + (size_t)cr0 * 512;
    const ushort_t* ar1 = y + (size_t)cr1 * 512;

    for (int c = 0; c < 4; ++c) {
        __syncthreads();
        {
            int o = tid >> 4;
            int j = (tid & 15) << 3;
            #pragma unroll
            for (int s = 0; s < 8; ++s, o += 16) {
                short8 v = *(const short8*)(btK + (size_t)o * 512 + c * 128 + j);
                *(short8*)(bs + o * LDSB_STRIDE + j) = v;
            }
        }
        __syncthreads();
        #pragma unroll
        for (int ksl = 0; ksl < 4; ++ksl) {
            int k0 = ksl * 32 + q * 8;
            short8 a0 = *(const short8*)(ar0 + c * 128 + k0);
            short8 a1 = *(const short8*)(ar1 + c * 128 + k0);
            #pragma unroll
            for (int t = 0; t < 8; ++t) {
                short8 b = *(const short8*)(bs + (t * 16 + r) * LDSB_STRIDE + k0);
                acc[0][t] = __builtin_amdgcn_mfma_f32_16x16x32_bf16(a0, b, acc[0][t], 0, 0, 0);
                acc[1][t] = __builtin_amdgcn_mfma_f32_16x16x32_bf16(a1, b, acc[1][t], 0, 0, 0);
            }
        }
    }
    #pragma unroll
    for (int i = 0; i < 2; ++i) {
        int rbase = m0 + w * 32 + i * 16 + (q << 2);
        float d[4];
        #pragma unroll
        for (int ii = 0; ii < 4; ++ii) {
            int rr = rbase + ii;
            d[ii] = fmaxf((float)cnt[(rr < N_NODES) ? rr : (N_NODES - 1)], 1.0f);
        }
        #pragma unroll
        for (int t = 0; t < 8; ++t) {
            int col = t * 16 + r;                 // D: col=lane&15, row=quad*4+reg
            float bb = canon[cbias + col];
            #pragma unroll
            for (int ii = 0; ii < 4; ++ii) {
                int rr = rbase + ii;
                if (rr < N_NODES) {
                    float v = acc[i][t][ii] / d[ii] + bb;
                    if (dorelu) v = fmaxf(v, 0.f);
                    xout[(size_t)rr * 128 + col] = f2bf(v);
                }
            }
        }
    }
}

// ---------------- DistMult on bf16 x2: 8 lanes/edge, 8 edges/wave ----------------
// NO device-scope fences/atomics here (R5 lesson: 2048 per-block release fences
// flushed XCD L2 under the gather working set, 44us -> 102us).
__global__ void k_distmult8b(const ushort_t* __restrict__ x2, const float* __restrict__ canon,
                             const int* __restrict__ ei, const int* __restrict__ et,
                             const int* __restrict__ neg, float* __restrict__ outp,
                             float* __restrict__ partials) {
    __shared__ float srel[1536];                  // 12 rel x 128, 6 KB
    int tid = threadIdx.x;
    for (int i = tid; i < 1536; i += 256) srel[i] = canon[C_REL + i];
    __syncthreads();
    int lane = tid & 63;
    int g = lane >> 3;
    int l = lane & 7;
    int w = (blockIdx.x * blockDim.x + tid) >> 6;
    int nw = (DM_BLOCKS * 256) >> 6;
    float aL1 = 0.f, aL2 = 0.f, aA = 0.f;
    for (int gid = w; gid < N_GROUPS; gid += nw) {
        int e = gid * 8 + g;
        int h = ei[e], t = ei[N_EDGE + e], r = et[e], qn = neg[e];
        const ushort_t* ph = x2 + (size_t)h * 128 + l * 16;
        const ushort_t* pt = x2 + (size_t)t * 128 + l * 16;
        const ushort_t* pq = x2 + (size_t)qn * 128 + l * 16;
        const float*    pr = srel + r * 128 + l * 16;
        short8 h0 = *(const short8*)ph, h1 = *(const short8*)(ph + 8);
        short8 t0 = *(const short8*)pt, t1 = *(const short8*)(pt + 8);
        short8 q0 = *(const short8*)pq, q1 = *(const short8*)(pq + 8);
        float sp = 0.f, sn = 0.f;
        #pragma unroll
        for (int j = 0; j < 8; ++j) {
            float hv = bf2f(((const ushort_t*)&h0)[j]) * pr[j];
            sp += hv * bf2f(((const ushort_t*)&t0)[j]);
            sn += hv * bf2f(((const ushort_t*)&q0)[j]);
        }
        #pragma unroll
        for (int j = 0; j < 8; ++j) {
            float hv = bf2f(((const ushort_t*)&h1)[j]) * pr[8 + j];
            sp += hv * bf2f(((const ushort_t*)&t1)[j]);
            sn += hv * bf2f(((const ushort_t*)&q1)[j]);
        }
        sp += __shfl_down(sp, 4); sn += __shfl_down(sn, 4);
        sp += __shfl_down(sp, 2); sn += __shfl_down(sn, 2);
        sp += __shfl_down(sp, 1); sn += __shfl_down(sn, 1);
        if (l == 0) {
            outp[e] = sp;
            aL1 += softplus(-sp);
            aL2 += softplus(sn);
            aA  += (sp > sn) ? 1.0f : 0.0f;
        }
    }
    #pragma unroll
    for (int off = 32; off; off >>= 1) {
        aL1 += __shfl_down(aL1, off);
        aL2 += __shfl_down(aL2, off);
        aA  += __shfl_down(aA,  off);
    }
    __shared__ float s[3][4];
    int wl = tid >> 6;
    if (lane == 0) { s[0][wl] = aL1; s[1][wl] = aL2; s[2][wl] = aA; }
    __syncthreads();
    if (tid == 0) {
        float t0 = 0.f, t1 = 0.f, t2 = 0.f;
        for (int i = 0; i < 4; ++i) { t0 += s[0][i]; t1 += s[1][i]; t2 += s[2][i]; }
        partials[blockIdx.x * 3 + 0] = t0;
        partials[blockIdx.x * 3 + 1] = t1;
        partials[blockIdx.x * 3 + 2] = t2;
    }
}

__global__ void k_final(const float* __restrict__ partials, float* __restrict__ outp) {
    __shared__ float s[3][256];
    int tid = threadIdx.x;
    float t0 = 0.f, t1 = 0.f, t2 = 0.f;
    for (int i = tid; i < DM_BLOCKS; i += 256) {
        t0 += partials[i * 3 + 0];
        t1 += partials[i * 3 + 1];
        t2 += partials[i * 3 + 2];
    }
    s[0][tid] = t0; s[1][tid] = t1; s[2][tid] = t2;
    __syncthreads();
    for (int st = 128; st; st >>= 1) {
        if (tid < st) {
            s[0][tid] += s[0][tid + st];
            s[1][tid] += s[1][tid + st];
            s[2][tid] += s[2][tid + st];
        }
        __syncthreads();
    }
    if (tid == 0) {
        float inv = 1.0f / (float)N_EDGE;
        outp[N_EDGE]     = 0.5f * (s[0][0] * inv + s[1][0] * inv);
        outp[N_EDGE + 1] = s[2][0] * inv;
    }
}

extern "C" void kernel_launch(void* const* d_in, const int* in_sizes, int n_in,
                              void* d_out, int out_size, void* d_ws, size_t ws_size,
                              hipStream_t stream) {
    const void* emb    = d_in[0];
    const void* ebias  = d_in[1];
    const void* bases1 = d_in[2];
    const void* comp1  = d_in[3];
    const void* bias1  = d_in[4];
    const void* bases2 = d_in[5];
    const void* comp2  = d_in[6];
    const void* bias2  = d_in[7];
    const void* rel    = d_in[8];
    const int*  ei     = (const int*)d_in[9];
    const int*  et     = (const int*)d_in[10];
    const int*  neg    = (const int*)d_in[11];
    float*      outp   = (float*)d_out;

    char* ws = (char*)d_ws;
    size_t off = 0;
    auto alloc = [&](size_t bytes) { char* p = ws + off; off += (bytes + 255) & ~(size_t)255; return p; };
    int*          flag   = (int*)alloc(256);
    float*        canon  = (float*)alloc((size_t)C_TOTAL * 4);
    int*          cnt    = (int*)alloc((size_t)N_NODES * 4);
    int*          ptr    = (int*)alloc((size_t)(N_NODES + 1) * 4);
    int*          cursor = (int*)alloc((size_t)N_NODES * 4);
    int*          bsum   = (int*)alloc(SCAN_BLOCKS * 4);
    ushort_t*     btK1   = (ushort_t*)alloc((size_t)128 * 512 * 2);
    ushort_t*     btK2   = (ushort_t*)alloc((size_t)128 * 512 * 2);
    float*        part   = (float*)alloc((size_t)DM_BLOCKS * 3 * 4);
    unsigned int* packed = (unsigned int*)alloc((size_t)N_EDGE * 4);
    ushort_t*     x      = (ushort_t*)alloc((size_t)N_NODES * 128 * 2);   // 12.8 MB
    ushort_t*     y      = (ushort_t*)alloc((size_t)N_NODES * 512 * 2);   // 51.2 MB

    // 11 dispatches: memset->prep, scan2->scan3, cnt->init (independent block ranges).
    k_prep<<<1 + 196, 256, 0, stream>>>((const ushort_t*)emb, flag, comp1, comp2, bias1,
                                        bias2, rel, ebias, canon, cnt);
    k_init<<<512 + XOCT_BLOCKS + CNT_BLOCKS, 256, 0, stream>>>(
        bases1, btK1, bases2, btK2, emb, canon, x, flag, ei, cnt);
    k_scan1<<<SCAN_BLOCKS, 1024, 0, stream>>>(cnt, ptr, bsum);
    k_scan3<<<SCAN_BLOCKS, 1024, 0, stream>>>(ptr, cursor, bsum);
    k_fill<<<N_EDGE / 256, 256, 0, stream>>>(ei, et, cursor, packed);

    int ggrid = (N_NODES + 127) / 128;   // 391

    // layer 1: y = gather(comp1 (x) x);  x <- bf16(relu(y@W1 / deg + bias1))
    k_agg2<<<N_NODES / 8, 256, 0, stream>>>(x, ptr, packed, canon + C_COMP1, y);
    k_gemm512<<<ggrid, 256, 0, stream>>>(y, btK1, cnt, canon, x, C_BIAS1, 1);

    // layer 2: y = gather(comp2 (x) x);  x <- bf16(y@W2 / deg + bias2)   (= x2)
    k_agg2<<<N_NODES / 8, 256, 0, stream>>>(x, ptr, packed, canon + C_COMP2, y);
    k_gemm512<<<ggrid, 256, 0, stream>>>(y, btK2, cnt, canon, x, C_BIAS2, 0);

    // decode + loss
    k_distmult8b<<<DM_BLOCKS, 256, 0, stream>>>(x, canon, ei, et, neg, outp, part);
    k_final<<<1, 256, 0, stream>>>(part, outp);
}